// Round 2
// baseline (1032.982 us; speedup 1.0000x reference)
//
#include <hip/hip_runtime.h>
#include <hip/hip_bf16.h>
#include <math.h>

// Problem constants
#define N_   16
#define A_   64
#define HW_  256
#define B_   32
#define C_   16
#define PP_  16
#define D_   16
#define OCH  544   // B_*PP_ + B_

// ws layout (in floats)
#define F_CONV 0u              // 2228224
#define F_MOM  2228224u        // 3*8*256*33 = 202752
#define F_BNP  2430976u        // 128
#define F_MJ   2431104u        // 4096
#define F_IP   2435200u        // 4096
#define F_BASE 2439296u        // 256
#define F_NU   2439552u        // 256
#define F_EPI  2439808u        // 256
#define F_ELAM 2440064u        // 256

__device__ __forceinline__ float digamma_f(float x){
    // valid for x >= ~1 (all call sites here); shift to x>=8 then asymptotic
    float r = 0.f;
    while (x < 8.f){ r -= 1.f/x; x += 1.f; }
    float inv = 1.f/x, inv2 = inv*inv;
    float p = logf(x) - 0.5f*inv
            - inv2*(0.08333333333333333f - inv2*(0.008333333333333333f - inv2*0.003968253968253968f));
    return r + p;
}

// ---------------- conv 1x1: out[n,o,s] = sum_a x[n,a,s]*w[o,a] ----------------
__global__ __launch_bounds__(256) void k_conv(const float* __restrict__ x,
    const float* __restrict__ wgt, float* __restrict__ out)
{
    const int g = blockIdx.x;      // o-group of 16 (0..33)
    const int n = blockIdx.y;      // 0..15
    const int t = threadIdx.x;     // site 0..255
    __shared__ float sw[16*64];
    ((float4*)sw)[t] = ((const float4*)(wgt + (size_t)g*16*64))[t];
    __syncthreads();
    const float* xp = x + (size_t)n*A_*HW_ + t;
    float acc[16];
#pragma unroll
    for (int i=0;i<16;i++) acc[i]=0.f;
#pragma unroll 4
    for (int a=0;a<A_;a++){
        float xv = xp[(size_t)a*HW_];
#pragma unroll
        for (int oo=0;oo<16;oo++) acc[oo] = fmaf(xv, sw[oo*64+a], acc[oo]);
    }
    float* op = out + ((size_t)n*OCH + g*16)*HW_ + t;
#pragma unroll
    for (int oo=0;oo<16;oo++) op[(size_t)oo*HW_] = acc[oo];
}

// ---------------- BN stats: scale/shift per b for poses and acts ----------------
__global__ __launch_bounds__(256) void k_bnstat(const float* __restrict__ conv,
    const float* __restrict__ gp, const float* __restrict__ bp,
    const float* __restrict__ ga, const float* __restrict__ bb,
    float* __restrict__ bnp)
{
    const int b = blockIdx.x;   // 0..31 poses, 32..63 acts
    const int t = threadIdx.x;  // site
    float sum=0.f, sq=0.f, cnt;
    if (b < 32){
        const float* p = conv + (size_t)(b*16)*HW_ + t;
        for (int n=0;n<16;n++)
            for (int pp=0;pp<16;pp++){
                float v = p[((size_t)n*OCH + pp)*HW_];
                sum += v; sq = fmaf(v, v, sq);
            }
        cnt = 65536.f;
    } else {
        const float* p = conv + (size_t)(512 + (b-32))*HW_ + t;
        for (int n=0;n<16;n++){
            float v = p[(size_t)n*OCH*HW_];
            sum += v; sq = fmaf(v, v, sq);
        }
        cnt = 4096.f;
    }
#pragma unroll
    for (int off=32; off>=1; off>>=1){
        sum += __shfl_xor(sum, off, 64);
        sq  += __shfl_xor(sq,  off, 64);
    }
    __shared__ float red[8];
    if ((t&63)==0){ red[t>>6]=sum; red[4+(t>>6)]=sq; }
    __syncthreads();
    if (t==0){
        float S = red[0]+red[1]+red[2]+red[3];
        float Q = red[4]+red[5]+red[6]+red[7];
        float mean = S/cnt, var = Q/cnt - mean*mean;
        float rs = rsqrtf(var + 1e-5f);
        if (b < 32){
            float sc = gp[b]*rs;
            bnp[b] = sc; bnp[32+b] = bp[b] - mean*sc;
        } else {
            int bx = b-32;
            float sc = ga[bx]*rs;
            bnp[64+bx] = sc; bnp[96+bx] = bb[bx] - mean*sc;
        }
    }
}

// ---------------- fused E-step + moments pass ----------------
// grid (16 chunks, 32 b), 256 threads = (n,c). chunk = 16 sites.
// FIRST=1: R_ij = 1/C (no softmax). Otherwise softmax from derive params.
template<int FIRST>
__global__ __launch_bounds__(256) void k_pass(const float* __restrict__ conv,
    const float* __restrict__ Wij, const float* __restrict__ bnp,
    const float* __restrict__ mjG, const float* __restrict__ ipG,
    const float* __restrict__ baseG, const float* __restrict__ nuG,
    float* __restrict__ Mom)
{
    const int chunk = blockIdx.x;   // 0..15
    const int b     = blockIdx.y;   // 0..31
    const int s0    = chunk*16;
    const int t = threadIdx.x;
    const int n = t>>4, c = t&15;

    __shared__ float shP[16*16*20];   // [si][n][pp pad20]
    __shared__ float shW[16*16*20];   // [si][c][mj pad20]
    __shared__ float shA[16*16];      // [n][si]

    {
        const float sc = bnp[b], sh = bnp[32+b];
        const int ln = t>>4, lp = t&15;
        const float* src = conv + ((size_t)ln*OCH + b*16 + lp)*HW_ + s0;
#pragma unroll
        for (int si=0; si<16; si+=4){
            float4 v = *(const float4*)(src+si);
            shP[(si+0)*320 + ln*20 + lp] = fmaf(v.x,sc,sh);
            shP[(si+1)*320 + ln*20 + lp] = fmaf(v.y,sc,sh);
            shP[(si+2)*320 + ln*20 + lp] = fmaf(v.z,sc,sh);
            shP[(si+3)*320 + ln*20 + lp] = fmaf(v.w,sc,sh);
        }
        const float* wsrc = Wij + ((size_t)(b*16 + ln)*16 + lp)*HW_ + s0;
#pragma unroll
        for (int si=0; si<16; si+=4){
            float4 v = *(const float4*)(wsrc+si);
            shW[(si+0)*320 + ln*20 + lp] = v.x;
            shW[(si+1)*320 + ln*20 + lp] = v.y;
            shW[(si+2)*320 + ln*20 + lp] = v.z;
            shW[(si+3)*320 + ln*20 + lp] = v.w;
        }
        if (t < 16){
            const float sa = bnp[64+b], ha = bnp[96+b];
            const float* asrc = conv + ((size_t)t*OCH + 512 + b)*HW_ + s0;
#pragma unroll
            for (int si=0; si<16; si+=4){
                float4 v = *(const float4*)(asrc+si);
                shA[t*16+si+0] = 1.f/(1.f+expf(-fmaf(v.x,sa,ha)));
                shA[t*16+si+1] = 1.f/(1.f+expf(-fmaf(v.y,sa,ha)));
                shA[t*16+si+2] = 1.f/(1.f+expf(-fmaf(v.z,sa,ha)));
                shA[t*16+si+3] = 1.f/(1.f+expf(-fmaf(v.w,sa,ha)));
            }
        }
    }

    float mj[16], ip[16], basev=0.f, nuv=0.f;
    if (!FIRST){
#pragma unroll
        for (int d=0; d<16; d+=4){
            float4 v = *(const float4*)(mjG + (size_t)t*16 + d);
            mj[d]=v.x; mj[d+1]=v.y; mj[d+2]=v.z; mj[d+3]=v.w;
            float4 u = *(const float4*)(ipG + (size_t)t*16 + d);
            ip[d]=u.x; ip[d+1]=u.y; ip[d+2]=u.z; ip[d+3]=u.w;
        }
        basev = baseG[t]; nuv = nuG[t];
    }
    __syncthreads();

    float racc=0.f, s1[16], s2[16];
#pragma unroll
    for (int d=0;d<16;d++){ s1[d]=0.f; s2[d]=0.f; }

    for (int si=0; si<16; ++si){
        float P[16], Wv[16];
        const float* pb = shP + si*320 + n*20;
        const float* wb = shW + si*320 + c*20;
#pragma unroll
        for (int i=0;i<16;i+=4){
            float4 v = *(const float4*)(pb+i);
            P[i]=v.x; P[i+1]=v.y; P[i+2]=v.z; P[i+3]=v.w;
            float4 u = *(const float4*)(wb+i);
            Wv[i]=u.x; Wv[i+1]=u.y; Wv[i+2]=u.z; Wv[i+3]=u.w;
        }
        float V[16];
#pragma unroll
        for (int a=0;a<4;a++){
#pragma unroll
            for (int j=0;j<4;j++){
                float acc = P[a*4+0]*Wv[0*4+j];
                acc = fmaf(P[a*4+1], Wv[1*4+j], acc);
                acc = fmaf(P[a*4+2], Wv[2*4+j], acc);
                acc = fmaf(P[a*4+3], Wv[3*4+j], acc);
                V[a*4+j] = acc;
            }
        }
        const float av = shA[n*16+si];
        float r;
        if (FIRST){
            r = 0.0625f * av;
        } else {
            float q = 0.f;
#pragma unroll
            for (int d=0;d<16;d++){
                float dv = V[d]-mj[d];
                q = fmaf(dv*ip[d], dv, q);
            }
            float arg = fmaf(-0.5f*nuv, q, basev);
            float mx = arg;
#pragma unroll
            for (int off=8; off>=1; off>>=1) mx = fmaxf(mx, __shfl_xor(mx, off, 64));
            float e = expf(arg-mx);
            float ssum = e;
#pragma unroll
            for (int off=8; off>=1; off>>=1) ssum += __shfl_xor(ssum, off, 64);
            r = (e/ssum)*av;
        }
        racc += r;
#pragma unroll
        for (int d=0;d<16;d++){
            s1[d] = fmaf(r, V[d], s1[d]);
            s2[d] = fmaf(r*V[d], V[d], s2[d]);
        }
    }

    float* mp = Mom + ((size_t)(b>>2)*256 + t)*33;
    atomicAdd(mp, racc);
#pragma unroll
    for (int d=0;d<16;d++){
        atomicAdd(mp+1+d,  s1[d]);
        atomicAdd(mp+17+d, s2[d]);
    }
}

// ---------------- derive: per-(n,c) M-step params ----------------
__global__ __launch_bounds__(256) void k_derive(const float* __restrict__ Mom,
    float* __restrict__ mjG, float* __restrict__ ipG, float* __restrict__ baseG,
    float* __restrict__ nuG, float* __restrict__ EpiG, float* __restrict__ ElamG)
{
    const int t = threadIdx.x;   // cell = n*16+c
    float M[33];
#pragma unroll
    for (int k=0;k<33;k++) M[k]=0.f;
    for (int bf=0; bf<8; bf++){
        const float* mp = Mom + ((size_t)bf*256 + t)*33;
#pragma unroll
        for (int k=0;k<33;k++) M[k] += mp[k];
    }
    float Rj  = M[0];
    float kap = 1.f + Rj;        // alpha == kappa (ALPHA0==KAPPA0==1)
    float nu  = 17.f + Rj;       // NU0 = D+1
    float ik  = 1.f/kap;
    float lndet = 0.f;
#pragma unroll
    for (int d=0; d<16; d++){
        float S1 = M[1+d], S2 = M[17+d];
        float m    = S1*ik;
        float iPsi = 1.f + S2 - S1*S1*ik;
        mjG[(size_t)t*16+d] = m;
        ipG[(size_t)t*16+d] = 1.f/iPsi;
        lndet -= logf(iPsi);
    }
    float El = lndet + 11.090354888959125f;   // + D*ln2
#pragma unroll
    for (int d=0; d<16; d++) El += digamma_f(0.5f*(nu - (float)d));
    float asum = kap;
#pragma unroll
    for (int off=8; off>=1; off>>=1) asum += __shfl_xor(asum, off, 64);
    float Epi = digamma_f(kap) - digamma_f(asum);
    nuG[t]   = nu;
    EpiG[t]  = Epi;
    ElamG[t] = El;
    // base = Elnpi + 0.5*Elnlam - 0.5*D*ln(2pi) - 0.5*D/kappa
    baseG[t] = Epi + 0.5f*El - 14.703016531274762f - 8.f*ik;
}

// ---------------- final: BN(m_j) per c, BN(a_raw) per c, sigmoid ----------------
__global__ __launch_bounds__(256) void k_final(const float* __restrict__ mjG,
    const float* __restrict__ EpiG, const float* __restrict__ ElamG,
    const float* __restrict__ bu, const float* __restrict__ ba,
    float* __restrict__ out)
{
    const int c = blockIdx.x;
    const int t = threadIdx.x;
    const int n = t>>4, d = t&15;
    float mv = mjG[(size_t)(n*16+c)*16 + d];
    float s = mv, q = mv*mv;
#pragma unroll
    for (int off=32; off>=1; off>>=1){
        s += __shfl_xor(s, off, 64);
        q += __shfl_xor(q, off, 64);
    }
    __shared__ float red[8];
    if ((t&63)==0){ red[t>>6]=s; red[4+(t>>6)]=q; }
    __syncthreads();
    float S = red[0]+red[1]+red[2]+red[3];
    float Q = red[4]+red[5]+red[6]+red[7];
    float mean = S*(1.f/256.f);
    float var  = Q*(1.f/256.f) - mean*mean;
    float rs   = rsqrtf(var + 1e-5f);
    out[256 + (size_t)(n*16+c)*16 + d] = (mv-mean)*rs;

    if (t < 16){
        const int nn = t;
        float Ep = EpiG[nn*16+c], El = ElamG[nn*16+c];
        float Hq = 22.703016531274762f - 0.5f*El;   // 0.5*D*ln(2*pi*e) - 0.5*Elnlam
        float araw = ba[c] - (expf(Ep)*Hq + bu[c]);
        float as = araw, aq = araw*araw;
#pragma unroll
        for (int off=8; off>=1; off>>=1){
            as += __shfl_xor(as, off, 64);
            aq += __shfl_xor(aq, off, 64);
        }
        float am  = as*(1.f/16.f);
        float av  = aq*(1.f/16.f) - am*am;
        float ars = rsqrtf(av + 1e-5f);
        float z = (araw-am)*ars;
        out[nn*16+c] = 1.f/(1.f+expf(-z));
    }
}

extern "C" void kernel_launch(void* const* d_in, const int* in_sizes, int n_in,
                              void* d_out, int out_size, void* d_ws, size_t ws_size,
                              hipStream_t stream)
{
    const float* x   = (const float*)d_in[0];
    const float* pw  = (const float*)d_in[1];
    const float* gp  = (const float*)d_in[2];
    const float* bp  = (const float*)d_in[3];
    const float* ga  = (const float*)d_in[4];
    const float* bb  = (const float*)d_in[5];
    const float* Wij = (const float*)d_in[6];
    const float* bu  = (const float*)d_in[7];
    const float* ba  = (const float*)d_in[8];
    float* out = (float*)d_out;
    float* ws  = (float*)d_ws;

    float* conv = ws + F_CONV;
    float* Mom  = ws + F_MOM;
    float* bnp  = ws + F_BNP;
    float* mj   = ws + F_MJ;
    float* ip   = ws + F_IP;
    float* base = ws + F_BASE;
    float* nu   = ws + F_NU;
    float* Epi  = ws + F_EPI;
    float* Elam = ws + F_ELAM;

    hipMemsetAsync(Mom, 0, (size_t)202752*4, stream);
    k_conv<<<dim3(34,16), 256, 0, stream>>>(x, pw, conv);
    k_bnstat<<<64, 256, 0, stream>>>(conv, gp, bp, ga, bb, bnp);
    for (int it=0; it<3; ++it){
        float* M = Mom + (size_t)it*8*256*33;
        if (it==0) k_pass<1><<<dim3(16,32), 256, 0, stream>>>(conv, Wij, bnp, mj, ip, base, nu, M);
        else       k_pass<0><<<dim3(16,32), 256, 0, stream>>>(conv, Wij, bnp, mj, ip, base, nu, M);
        k_derive<<<1, 256, 0, stream>>>(M, mj, ip, base, nu, Epi, Elam);
    }
    k_final<<<16, 256, 0, stream>>>(mj, Epi, Elam, bu, ba, out);
}

// Round 3
// 193.748 us; speedup vs baseline: 5.3316x; 5.3316x over previous
//
#include <hip/hip_runtime.h>
#include <hip/hip_bf16.h>
#include <math.h>

// Problem constants
#define N_   16
#define A_   64
#define HW_  256
#define B_   32
#define C_   16
#define PP_  16
#define D_   16
#define OCH  544   // B_*PP_ + B_

// ---- primary ws layout (floats), needs 26.6 MB ----
#define F_CONV 0u              // 2228224
#define F_PART 2228224u        // 512*33*256 = 4325376
#define F_RED  6553600u        // 8*33*256   = 67584
#define F_BNP  6621184u        // 128
#define F_MJ   6621312u        // 4096
#define F_IP   6625408u        // 4096
#define F_BASE 6629504u        // 256
#define F_NU   6629760u        // 256
#define F_EPI  6630016u        // 256
#define F_ELAM 6630272u        // 256
#define WS_NEED ((size_t)6630528u * 4u)

__device__ __forceinline__ float digamma_f(float x){
    // valid for x >= ~1 (all call sites here); shift to x>=8 then asymptotic
    float r = 0.f;
    while (x < 8.f){ r -= 1.f/x; x += 1.f; }
    float inv = 1.f/x, inv2 = inv*inv;
    float p = logf(x) - 0.5f*inv
            - inv2*(0.08333333333333333f - inv2*(0.008333333333333333f - inv2*0.003968253968253968f));
    return r + p;
}

// ---------------- conv 1x1: out[n,o,s] = sum_a x[n,a,s]*w[o,a] ----------------
__global__ __launch_bounds__(256) void k_conv(const float* __restrict__ x,
    const float* __restrict__ wgt, float* __restrict__ out)
{
    const int g = blockIdx.x;      // o-group of 16 (0..33)
    const int n = blockIdx.y;      // 0..15
    const int t = threadIdx.x;     // site 0..255
    __shared__ float sw[16*64];
    ((float4*)sw)[t] = ((const float4*)(wgt + (size_t)g*16*64))[t];
    __syncthreads();
    const float* xp = x + (size_t)n*A_*HW_ + t;
    float acc[16];
#pragma unroll
    for (int i=0;i<16;i++) acc[i]=0.f;
#pragma unroll 4
    for (int a=0;a<A_;a++){
        float xv = xp[(size_t)a*HW_];
#pragma unroll
        for (int oo=0;oo<16;oo++) acc[oo] = fmaf(xv, sw[oo*64+a], acc[oo]);
    }
    float* op = out + ((size_t)n*OCH + g*16)*HW_ + t;
#pragma unroll
    for (int oo=0;oo<16;oo++) op[(size_t)oo*HW_] = acc[oo];
}

// ---------------- BN stats: scale/shift per b for poses and acts ----------------
__global__ __launch_bounds__(256) void k_bnstat(const float* __restrict__ conv,
    const float* __restrict__ gp, const float* __restrict__ bp,
    const float* __restrict__ ga, const float* __restrict__ bb,
    float* __restrict__ bnp)
{
    const int b = blockIdx.x;   // 0..31 poses, 32..63 acts
    const int t = threadIdx.x;  // site
    float sum=0.f, sq=0.f, cnt;
    if (b < 32){
        const float* p = conv + (size_t)(b*16)*HW_ + t;
        for (int n=0;n<16;n++)
            for (int pp=0;pp<16;pp++){
                float v = p[((size_t)n*OCH + pp)*HW_];
                sum += v; sq = fmaf(v, v, sq);
            }
        cnt = 65536.f;
    } else {
        const float* p = conv + (size_t)(512 + (b-32))*HW_ + t;
        for (int n=0;n<16;n++){
            float v = p[(size_t)n*OCH*HW_];
            sum += v; sq = fmaf(v, v, sq);
        }
        cnt = 4096.f;
    }
#pragma unroll
    for (int off=32; off>=1; off>>=1){
        sum += __shfl_xor(sum, off, 64);
        sq  += __shfl_xor(sq,  off, 64);
    }
    __shared__ float red[8];
    if ((t&63)==0){ red[t>>6]=sum; red[4+(t>>6)]=sq; }
    __syncthreads();
    if (t==0){
        float S = red[0]+red[1]+red[2]+red[3];
        float Q = red[4]+red[5]+red[6]+red[7];
        float mean = S/cnt, var = Q/cnt - mean*mean;
        float rs = rsqrtf(var + 1e-5f);
        if (b < 32){
            float sc = gp[b]*rs;
            bnp[b] = sc; bnp[32+b] = bp[b] - mean*sc;
        } else {
            int bx = b-32;
            float sc = ga[bx]*rs;
            bnp[64+bx] = sc; bnp[96+bx] = bb[bx] - mean*sc;
        }
    }
}

// ---------------- fused E-step + moments pass ----------------
// grid (16 chunks, 32 b), 256 threads = (n,c). chunk = 16 sites.
// FIRST=1: R_ij = 1/C (no softmax). STORE=1: per-block partial stores
// into Part[blk][33][256]; STORE=0: legacy atomic path into Mom buckets.
template<int FIRST, int STORE>
__global__ __launch_bounds__(256) void k_pass(const float* __restrict__ conv,
    const float* __restrict__ Wij, const float* __restrict__ bnp,
    const float* __restrict__ mjG, const float* __restrict__ ipG,
    const float* __restrict__ baseG, const float* __restrict__ nuG,
    float* __restrict__ Out)
{
    const int chunk = blockIdx.x;   // 0..15
    const int b     = blockIdx.y;   // 0..31
    const int s0    = chunk*16;
    const int t = threadIdx.x;
    const int n = t>>4, c = t&15;

    __shared__ float shP[16*16*20];   // [si][n][pp pad20]
    __shared__ float shW[16*16*20];   // [si][c][mj pad20]
    __shared__ float shA[16*16];      // [n][si]

    {
        const float sc = bnp[b], sh = bnp[32+b];
        const int ln = t>>4, lp = t&15;
        const float* src = conv + ((size_t)ln*OCH + b*16 + lp)*HW_ + s0;
#pragma unroll
        for (int si=0; si<16; si+=4){
            float4 v = *(const float4*)(src+si);
            shP[(si+0)*320 + ln*20 + lp] = fmaf(v.x,sc,sh);
            shP[(si+1)*320 + ln*20 + lp] = fmaf(v.y,sc,sh);
            shP[(si+2)*320 + ln*20 + lp] = fmaf(v.z,sc,sh);
            shP[(si+3)*320 + ln*20 + lp] = fmaf(v.w,sc,sh);
        }
        const float* wsrc = Wij + ((size_t)(b*16 + ln)*16 + lp)*HW_ + s0;
#pragma unroll
        for (int si=0; si<16; si+=4){
            float4 v = *(const float4*)(wsrc+si);
            shW[(si+0)*320 + ln*20 + lp] = v.x;
            shW[(si+1)*320 + ln*20 + lp] = v.y;
            shW[(si+2)*320 + ln*20 + lp] = v.z;
            shW[(si+3)*320 + ln*20 + lp] = v.w;
        }
        if (t < 16){
            const float sa = bnp[64+b], ha = bnp[96+b];
            const float* asrc = conv + ((size_t)t*OCH + 512 + b)*HW_ + s0;
#pragma unroll
            for (int si=0; si<16; si+=4){
                float4 v = *(const float4*)(asrc+si);
                shA[t*16+si+0] = 1.f/(1.f+expf(-fmaf(v.x,sa,ha)));
                shA[t*16+si+1] = 1.f/(1.f+expf(-fmaf(v.y,sa,ha)));
                shA[t*16+si+2] = 1.f/(1.f+expf(-fmaf(v.z,sa,ha)));
                shA[t*16+si+3] = 1.f/(1.f+expf(-fmaf(v.w,sa,ha)));
            }
        }
    }

    float mj[16], ip[16], basev=0.f, nuv=0.f;
    if (!FIRST){
#pragma unroll
        for (int d=0; d<16; d+=4){
            float4 v = *(const float4*)(mjG + (size_t)t*16 + d);
            mj[d]=v.x; mj[d+1]=v.y; mj[d+2]=v.z; mj[d+3]=v.w;
            float4 u = *(const float4*)(ipG + (size_t)t*16 + d);
            ip[d]=u.x; ip[d+1]=u.y; ip[d+2]=u.z; ip[d+3]=u.w;
        }
        basev = baseG[t]; nuv = nuG[t];
    }
    __syncthreads();

    float racc=0.f, s1[16], s2[16];
#pragma unroll
    for (int d=0;d<16;d++){ s1[d]=0.f; s2[d]=0.f; }

    for (int si=0; si<16; ++si){
        float P[16], Wv[16];
        const float* pb = shP + si*320 + n*20;
        const float* wb = shW + si*320 + c*20;
#pragma unroll
        for (int i=0;i<16;i+=4){
            float4 v = *(const float4*)(pb+i);
            P[i]=v.x; P[i+1]=v.y; P[i+2]=v.z; P[i+3]=v.w;
            float4 u = *(const float4*)(wb+i);
            Wv[i]=u.x; Wv[i+1]=u.y; Wv[i+2]=u.z; Wv[i+3]=u.w;
        }
        float V[16];
#pragma unroll
        for (int a=0;a<4;a++){
#pragma unroll
            for (int j=0;j<4;j++){
                float acc = P[a*4+0]*Wv[0*4+j];
                acc = fmaf(P[a*4+1], Wv[1*4+j], acc);
                acc = fmaf(P[a*4+2], Wv[2*4+j], acc);
                acc = fmaf(P[a*4+3], Wv[3*4+j], acc);
                V[a*4+j] = acc;
            }
        }
        const float av = shA[n*16+si];
        float r;
        if (FIRST){
            r = 0.0625f * av;
        } else {
            float q = 0.f;
#pragma unroll
            for (int d=0;d<16;d++){
                float dv = V[d]-mj[d];
                q = fmaf(dv*ip[d], dv, q);
            }
            float arg = fmaf(-0.5f*nuv, q, basev);
            float mx = arg;
#pragma unroll
            for (int off=8; off>=1; off>>=1) mx = fmaxf(mx, __shfl_xor(mx, off, 64));
            float e = expf(arg-mx);
            float ssum = e;
#pragma unroll
            for (int off=8; off>=1; off>>=1) ssum += __shfl_xor(ssum, off, 64);
            r = (e/ssum)*av;
        }
        racc += r;
#pragma unroll
        for (int d=0;d<16;d++){
            s1[d] = fmaf(r, V[d], s1[d]);
            s2[d] = fmaf(r*V[d], V[d], s2[d]);
        }
    }

    if (STORE){
        // Part[blk][k][t], blk = b*16+chunk, plain coalesced stores (no atomics)
        float* pp = Out + ((size_t)(b*16 + chunk)*33)*256 + t;
        pp[0] = racc;
#pragma unroll
        for (int d=0;d<16;d++){
            pp[(size_t)(1+d)*256]  = s1[d];
            pp[(size_t)(17+d)*256] = s2[d];
        }
    } else {
        float* mp = Out + ((size_t)(b>>2)*256 + t)*33;
        atomicAdd(mp, racc);
#pragma unroll
        for (int d=0;d<16;d++){
            atomicAdd(mp+1+d,  s1[d]);
            atomicAdd(mp+17+d, s2[d]);
        }
    }
}

// ---------------- reduce 512 partials -> Red[8][33][256] ----------------
__global__ __launch_bounds__(256) void k_reduce(const float* __restrict__ Part,
    float* __restrict__ Red)
{
    const int k = blockIdx.x;   // 0..32
    const int q = blockIdx.y;   // 0..7 (64 blks each)
    const int t = threadIdx.x;
    const size_t STR = 33u*256u;
    const float* src = Part + (size_t)q*64u*STR + (size_t)k*256u + t;
    float a0=0,a1=0,a2=0,a3=0,a4=0,a5=0,a6=0,a7=0;
#pragma unroll
    for (int i=0;i<64;i+=8){
        a0 += src[(size_t)(i+0)*STR];
        a1 += src[(size_t)(i+1)*STR];
        a2 += src[(size_t)(i+2)*STR];
        a3 += src[(size_t)(i+3)*STR];
        a4 += src[(size_t)(i+4)*STR];
        a5 += src[(size_t)(i+5)*STR];
        a6 += src[(size_t)(i+6)*STR];
        a7 += src[(size_t)(i+7)*STR];
    }
    Red[((size_t)q*33 + k)*256 + t] = ((a0+a1)+(a2+a3)) + ((a4+a5)+(a6+a7));
}

// ---------------- derive: per-(n,c) M-step params ----------------
// FROMRED=1: read Red[8][33][256]; FROMRED=0: read legacy Mom buckets.
template<int FROMRED>
__global__ __launch_bounds__(256) void k_derive(const float* __restrict__ Src,
    float* __restrict__ mjG, float* __restrict__ ipG, float* __restrict__ baseG,
    float* __restrict__ nuG, float* __restrict__ EpiG, float* __restrict__ ElamG)
{
    const int t = threadIdx.x;   // cell = n*16+c
    float M[33];
#pragma unroll
    for (int k=0;k<33;k++) M[k]=0.f;
    if (FROMRED){
        for (int q=0; q<8; q++){
            const float* rp = Src + (size_t)q*33u*256u + t;
#pragma unroll
            for (int k=0;k<33;k++) M[k] += rp[(size_t)k*256u];
        }
    } else {
        for (int bf=0; bf<8; bf++){
            const float* mp = Src + ((size_t)bf*256 + t)*33;
#pragma unroll
            for (int k=0;k<33;k++) M[k] += mp[k];
        }
    }
    float Rj  = M[0];
    float kap = 1.f + Rj;        // alpha == kappa (ALPHA0==KAPPA0==1)
    float nu  = 17.f + Rj;       // NU0 = D+1
    float ik  = 1.f/kap;
    float lndet = 0.f;
#pragma unroll
    for (int d=0; d<16; d++){
        float S1 = M[1+d], S2 = M[17+d];
        float m    = S1*ik;
        float iPsi = 1.f + S2 - S1*S1*ik;
        mjG[(size_t)t*16+d] = m;
        ipG[(size_t)t*16+d] = 1.f/iPsi;
        lndet -= logf(iPsi);
    }
    float El = lndet + 11.090354888959125f;   // + D*ln2
#pragma unroll
    for (int d=0; d<16; d++) El += digamma_f(0.5f*(nu - (float)d));
    float asum = kap;
#pragma unroll
    for (int off=8; off>=1; off>>=1) asum += __shfl_xor(asum, off, 64);
    float Epi = digamma_f(kap) - digamma_f(asum);
    nuG[t]   = nu;
    EpiG[t]  = Epi;
    ElamG[t] = El;
    // base = Elnpi + 0.5*Elnlam - 0.5*D*ln(2pi) - 0.5*D/kappa
    baseG[t] = Epi + 0.5f*El - 14.703016531274762f - 8.f*ik;
}

// ---------------- final: BN(m_j) per c, BN(a_raw) per c, sigmoid ----------------
__global__ __launch_bounds__(256) void k_final(const float* __restrict__ mjG,
    const float* __restrict__ EpiG, const float* __restrict__ ElamG,
    const float* __restrict__ bu, const float* __restrict__ ba,
    float* __restrict__ out)
{
    const int c = blockIdx.x;
    const int t = threadIdx.x;
    const int n = t>>4, d = t&15;
    float mv = mjG[(size_t)(n*16+c)*16 + d];
    float s = mv, q = mv*mv;
#pragma unroll
    for (int off=32; off>=1; off>>=1){
        s += __shfl_xor(s, off, 64);
        q += __shfl_xor(q, off, 64);
    }
    __shared__ float red[8];
    if ((t&63)==0){ red[t>>6]=s; red[4+(t>>6)]=q; }
    __syncthreads();
    float S = red[0]+red[1]+red[2]+red[3];
    float Q = red[4]+red[5]+red[6]+red[7];
    float mean = S*(1.f/256.f);
    float var  = Q*(1.f/256.f) - mean*mean;
    float rs   = rsqrtf(var + 1e-5f);
    out[256 + (size_t)(n*16+c)*16 + d] = (mv-mean)*rs;

    if (t < 16){
        const int nn = t;
        float Ep = EpiG[nn*16+c], El = ElamG[nn*16+c];
        float Hq = 22.703016531274762f - 0.5f*El;   // 0.5*D*ln(2*pi*e) - 0.5*Elnlam
        float araw = ba[c] - (expf(Ep)*Hq + bu[c]);
        float as = araw, aq = araw*araw;
#pragma unroll
        for (int off=8; off>=1; off>>=1){
            as += __shfl_xor(as, off, 64);
            aq += __shfl_xor(aq, off, 64);
        }
        float am  = as*(1.f/16.f);
        float av  = aq*(1.f/16.f) - am*am;
        float ars = rsqrtf(av + 1e-5f);
        float z = (araw-am)*ars;
        out[nn*16+c] = 1.f/(1.f+expf(-z));
    }
}

extern "C" void kernel_launch(void* const* d_in, const int* in_sizes, int n_in,
                              void* d_out, int out_size, void* d_ws, size_t ws_size,
                              hipStream_t stream)
{
    const float* x   = (const float*)d_in[0];
    const float* pw  = (const float*)d_in[1];
    const float* gp  = (const float*)d_in[2];
    const float* bp  = (const float*)d_in[3];
    const float* ga  = (const float*)d_in[4];
    const float* bb  = (const float*)d_in[5];
    const float* Wij = (const float*)d_in[6];
    const float* bu  = (const float*)d_in[7];
    const float* ba  = (const float*)d_in[8];
    float* out = (float*)d_out;
    float* ws  = (float*)d_ws;

    float* conv = ws + F_CONV;
    float* part = ws + F_PART;
    float* red  = ws + F_RED;
    float* bnp  = ws + F_BNP;
    float* mj   = ws + F_MJ;
    float* ip   = ws + F_IP;
    float* base = ws + F_BASE;
    float* nu   = ws + F_NU;
    float* Epi  = ws + F_EPI;
    float* Elam = ws + F_ELAM;

    k_conv<<<dim3(34,16), 256, 0, stream>>>(x, pw, conv);
    k_bnstat<<<64, 256, 0, stream>>>(conv, gp, bp, ga, bb, bnp);

    if (ws_size >= WS_NEED){
        // no-atomic path: per-block partial stores + hierarchical reduce
        for (int it=0; it<3; ++it){
            if (it==0) k_pass<1,1><<<dim3(16,32), 256, 0, stream>>>(conv, Wij, bnp, mj, ip, base, nu, part);
            else       k_pass<0,1><<<dim3(16,32), 256, 0, stream>>>(conv, Wij, bnp, mj, ip, base, nu, part);
            k_reduce<<<dim3(33,8), 256, 0, stream>>>(part, red);
            k_derive<1><<<1, 256, 0, stream>>>(red, mj, ip, base, nu, Epi, Elam);
        }
    } else {
        // fallback: legacy atomic path (Mom buckets live in the Part region)
        hipMemsetAsync(part, 0, (size_t)3*8*256*33*4, stream);
        for (int it=0; it<3; ++it){
            float* M = part + (size_t)it*8*256*33;
            if (it==0) k_pass<1,0><<<dim3(16,32), 256, 0, stream>>>(conv, Wij, bnp, mj, ip, base, nu, M);
            else       k_pass<0,0><<<dim3(16,32), 256, 0, stream>>>(conv, Wij, bnp, mj, ip, base, nu, M);
            k_derive<0><<<1, 256, 0, stream>>>(M, mj, ip, base, nu, Epi, Elam);
        }
    }
    k_final<<<16, 256, 0, stream>>>(mj, Epi, Elam, bu, ba, out);
}